// Round 1
// baseline (78.110 us; speedup 1.0000x reference)
//
#include <hip/hip_runtime.h>
#include <math.h>

#define NN 384
#define DD 128
#define MARGIN_F 0.2f
#define RHO_F 10.0f

// One block per anchor i. Computes the distance row d[i][:], then for each
// same-class pair (i,j) the semihard-max and hard-min reductions over k.
__global__ __launch_bounds__(256) void facenet_main(
    const int* __restrict__ classes,
    const float* __restrict__ emb,
    float* __restrict__ pnum,
    float* __restrict__ pden) {
  __shared__ float e_i[DD];
  __shared__ float d_row[NN];
  __shared__ int cls[NN];
  __shared__ float wnum[4];
  __shared__ float wden[4];

  const int i = blockIdx.x;
  const int tid = threadIdx.x;
  const int lane = tid & 63;
  const int wave = tid >> 6;

  if (tid < DD / 4) {
    ((float4*)e_i)[tid] = ((const float4*)(emb + (size_t)i * DD))[tid];
  }
  cls[tid] = classes[tid];
  if (tid < NN - 256) cls[tid + 256] = classes[tid + 256];
  __syncthreads();

  // d_row[j] = max(sq_i + sq_j - 2*dot(e_i,e_j), 0)  -- matches reference formula
  for (int j = tid; j < NN; j += 256) {
    const float4* ej = (const float4*)(emb + (size_t)j * DD);
    float dot = 0.f, sqj = 0.f, sqi = 0.f;
#pragma unroll
    for (int d4 = 0; d4 < DD / 4; ++d4) {
      const float4 a = ((const float4*)e_i)[d4];
      const float4 b = ej[d4];
      dot += a.x * b.x + a.y * b.y + a.z * b.z + a.w * b.w;
      sqj += b.x * b.x + b.y * b.y + b.z * b.z + b.w * b.w;
      sqi += a.x * a.x + a.y * a.y + a.z * a.z + a.w * a.w;
    }
    d_row[j] = fmaxf(sqi + sqj - 2.f * dot, 0.f);
  }
  __syncthreads();

  const int ci = cls[i];
  float num_w = 0.f;
  float den_w = 0.f;

  // Each wave owns a contiguous 96-wide chunk of j; branch is wave-uniform.
  const int j0 = wave * (NN / 4);
  const int j1 = j0 + (NN / 4);
  for (int j = j0; j < j1; ++j) {
    if (j == i || cls[j] != ci) continue;
    const float dij = d_row[j];
    float smax = 0.f;       // max over k of tl * semihard_indicator
    float smin = INFINITY;  // min over k of (tl - RHO * hard_indicator)
#pragma unroll
    for (int kk = 0; kk < NN / 64; ++kk) {
      const int k = lane + kk * 64;
      const float tl = fmaxf(MARGIN_F - (d_row[k] - dij), 0.f);
      const bool valid = (cls[k] != ci);
      const float semi_val = (valid && (tl > 0.f) && (tl <= MARGIN_F)) ? tl : 0.f;
      smax = fmaxf(smax, semi_val);
      const float shifted = (valid && (tl > MARGIN_F)) ? (tl - RHO_F) : tl;
      smin = fminf(smin, shifted);
    }
#pragma unroll
    for (int m = 1; m < 64; m <<= 1) {
      smax = fmaxf(smax, __shfl_xor(smax, m, 64));
      smin = fminf(smin, __shfl_xor(smin, m, 64));
    }
    const float hl = (smin < 0.f) ? (smin + RHO_F) : 0.f;
    const float ppl = smax + ((smax == 0.f) ? hl : 0.f);
    num_w += ppl;
    den_w += 1.f;
  }

  if (lane == 0) { wnum[wave] = num_w; wden[wave] = den_w; }
  __syncthreads();
  if (tid == 0) {
    pnum[i] = wnum[0] + wnum[1] + wnum[2] + wnum[3];
    pden[i] = wden[0] + wden[1] + wden[2] + wden[3];
  }
}

__global__ __launch_bounds__(256) void facenet_reduce(
    const float* __restrict__ pnum,
    const float* __restrict__ pden,
    float* __restrict__ out) {
  __shared__ float wnum[4], wden[4];
  const int tid = threadIdx.x;
  const int lane = tid & 63;
  const int wave = tid >> 6;
  float n = pnum[tid] + ((tid + 256 < NN) ? pnum[tid + 256] : 0.f);
  float d = pden[tid] + ((tid + 256 < NN) ? pden[tid + 256] : 0.f);
#pragma unroll
  for (int m = 1; m < 64; m <<= 1) {
    n += __shfl_xor(n, m, 64);
    d += __shfl_xor(d, m, 64);
  }
  if (lane == 0) { wnum[wave] = n; wden[wave] = d; }
  __syncthreads();
  if (tid == 0) {
    const float tn = wnum[0] + wnum[1] + wnum[2] + wnum[3];
    const float td = wden[0] + wden[1] + wden[2] + wden[3];
    out[0] = (td > 0.f) ? (tn / fmaxf(td, 1.f)) : 0.f;
  }
}

extern "C" void kernel_launch(void* const* d_in, const int* in_sizes, int n_in,
                              void* d_out, int out_size, void* d_ws, size_t ws_size,
                              hipStream_t stream) {
  const int* classes = (const int*)d_in[0];
  const float* emb = (const float*)d_in[1];
  float* out = (float*)d_out;
  float* pnum = (float*)d_ws;
  float* pden = pnum + NN;

  facenet_main<<<NN, 256, 0, stream>>>(classes, emb, pnum, pden);
  facenet_reduce<<<1, 256, 0, stream>>>(pnum, pden, out);
}